// Round 10
// baseline (246.613 us; speedup 1.0000x reference)
//
#include <hip/hip_runtime.h>
#include <hip/hip_bf16.h>
#include <stdint.h>

// B=8, T=4096, D=512, OUT=1. M = B*T = 32768.
// cast; fused gates GEMM (32x32x16 MFMA, ring-3 single-barrier, fused chunk
// summaries); pass2; pass3 (L0) / pass3+LN+proj fused (L1).

#define MROWS 32768
#define DDIM  512
#define TLEN  4096
#define BSZ   8
#define NCHUNK 64
#define CLEN   64

typedef __attribute__((ext_vector_type(8))) __bf16 bf16x8;
typedef __attribute__((ext_vector_type(16))) float f32x16;
typedef __attribute__((ext_vector_type(4))) unsigned short ushort4_t;

static __device__ __forceinline__ unsigned short f2bf(float f) {
    unsigned int u = __float_as_uint(f);
    u = (u + 0x7FFFu + ((u >> 16) & 1u)) >> 16;   // RNE
    return (unsigned short)u;
}
static __device__ __forceinline__ float bf2f(unsigned short s) {
    return __uint_as_float(((unsigned int)s) << 16);
}
static __device__ __forceinline__ void gload_lds16(const void* gptr, void* ldsp) {
    __builtin_amdgcn_global_load_lds(
        (const __attribute__((address_space(1))) uint32_t*)gptr,
        (__attribute__((address_space(3))) uint32_t*)ldsp,
        16, 0, 0);
}

#define WAITV(n) asm volatile("s_waitcnt vmcnt(" #n ")" ::: "memory")

// ---------------- merged fp32 -> bf16 cast (x + 6 W) ----------------
__global__ __launch_bounds__(256) void cast_all(
    const float4* __restrict__ x,
    const float4* __restrict__ w0, const float4* __restrict__ w1,
    const float4* __restrict__ w2, const float4* __restrict__ w3,
    const float4* __restrict__ w4, const float4* __restrict__ w5,
    ushort4_t* __restrict__ xb, ushort4_t* __restrict__ wb)
{
    int i = blockIdx.x * 256 + threadIdx.x;    // 0 .. 4587519
    float4 v;
    ushort4_t* dst;
    if (i < 4194304) {
        v = x[i];
        dst = xb + i;
    } else {
        int j = i - 4194304;
        int wsel = j >> 16;
        int rem = j & 65535;
        const float4* src = (wsel == 0) ? w0 : (wsel == 1) ? w1 : (wsel == 2) ? w2
                          : (wsel == 3) ? w3 : (wsel == 4) ? w4 : w5;
        v = src[rem];
        dst = wb + j;
    }
    ushort4_t o;
    o.x = f2bf(v.x); o.y = f2bf(v.y); o.z = f2bf(v.z); o.w = f2bf(v.w);
    *dst = o;
}

// ---------------- fused gate GEMM + chunk-summary epilogue ----------------
// 256 thr / 4 waves (2m x 2n), wave tile 64x32 via 32x32x16 MFMA (2 m-frags x
// 3 gates, acc 6x f32x16 = 96 AGPR). BM=128, BN=64, BK=32; 16 K-steps.
// LDS: ring-3 x (A[128][32] 8KB + 3x B[64][32] 4KB) = 3 x 20KB = 60KB.
// Per K-step: {vmcnt(5) counted; ONE barrier; STAGE t+2 (5 gload_lds);
//              10 ds_read_b128; setprio(1); 12 MFMA; setprio(0)}.
// Race-free: a wave at step-t's barrier has consumed all step-(t-1) LDS reads
// (lgkmcnt precedes its MFMAs), so staging buf[(t+2)%3]=buf[(t-1)%3] is safe.
// Swizzle: 16B-chunk cPhys = cLog ^ f(row), f(row) = ((row>>1)^(row>>3))&3 --
// covers all 8 bank-groups per 8-row window AND breaks 1KB periodicity.
// f is lane-constant for frag reads and slice-invariant for staging.
__global__ __launch_bounds__(256, 2) void gates_gemm(
    const unsigned short* __restrict__ X,
    const unsigned short* __restrict__ Wf,
    const unsigned short* __restrict__ Wi,
    const unsigned short* __restrict__ Wh,
    const float* __restrict__ bf_, const float* __restrict__ bi_,
    const float* __restrict__ bh_,
    unsigned int* __restrict__ au_out,
    float* __restrict__ Asum, float* __restrict__ Usum)
{
    __shared__ __align__(16) unsigned short lds[3 * 10240];   // 60 KB

    const int tid  = threadIdx.x;
    const int lane = tid & 63;
    const int wave = tid >> 6;                 // 0..3
    const int wm = wave >> 1;                  // 0..1 : 64-row strip (= one chunk)
    const int wn = wave & 1;                   // 0..1 : 32-col strip
    const int ln31 = lane & 31;
    const int kh = lane >> 5;                  // k-half for 32x32x16 frags

    // XCD-aware bijective swizzle: 2048 blocks; 8 bx of one by adjacent per XCD.
    const int w = blockIdx.x;
    const int xcd = w & 7;
    const int s = w >> 3;                      // 0..255
    const int by = xcd * 32 + (s >> 3);        // 0..255
    const int bx = s & 7;                      // 0..7
    const int mblk = by * 128;
    const int nblk = bx * 64;

    // staging: thread -> (srow = tid>>2 in 0..63, phys chunk c4 = tid&3);
    // global logical chunk = c4 ^ f(srow); f(64+srow) == f(srow).
    const int srow = tid >> 2;
    const int c4   = tid & 3;
    const int cg   = ((c4 ^ (((srow >> 1) ^ (srow >> 3)) & 3)) << 3);  // bf16 units
    const int tid8 = tid * 8;                                          // linear LDS dest
    const unsigned short* g0 = X  + (size_t)(mblk + srow) * 512 + cg;
    const unsigned short* g1 = X  + (size_t)(mblk + 64 + srow) * 512 + cg;
    const unsigned short* g2 = Wf + (size_t)(nblk + srow) * 512 + cg;
    const unsigned short* g3 = Wi + (size_t)(nblk + srow) * 512 + cg;
    const unsigned short* g4 = Wh + (size_t)(nblk + srow) * 512 + cg;

    // LDS read offsets (ushort units): row*32 + ((2ks+kh) ^ f(row))*8.
    // f(row) reduces to the lane constant fl for all fragment rows.
    const int fl = ((ln31 >> 1) ^ (ln31 >> 3)) & 3;
    int aoff[2][2], boff[2];
#pragma unroll
    for (int mi = 0; mi < 2; ++mi) {
        int row = wm * 64 + mi * 32 + ln31;
#pragma unroll
        for (int ks = 0; ks < 2; ++ks)
            aoff[mi][ks] = row * 32 + (((2 * ks + kh) ^ fl) << 3);
    }
    {
        int brow = wn * 32 + ln31;
#pragma unroll
        for (int ks = 0; ks < 2; ++ks)
            boff[ks] = brow * 32 + (((2 * ks + kh) ^ fl) << 3);
    }

    f32x16 accF[2], accI[2], accH[2];
#pragma unroll
    for (int mi = 0; mi < 2; ++mi) {
#pragma unroll
        for (int e = 0; e < 16; ++e) { accF[mi][e] = 0.f; accI[mi][e] = 0.f; accH[mi][e] = 0.f; }
    }

#define STAGE(bb) do { \
    gload_lds16(g0, lds + (bb) + tid8);            \
    gload_lds16(g1, lds + (bb) + 2048 + tid8);     \
    gload_lds16(g2, lds + (bb) + 4096 + tid8);     \
    gload_lds16(g3, lds + (bb) + 6144 + tid8);     \
    gload_lds16(g4, lds + (bb) + 8192 + tid8);     \
    g0 += 32; g1 += 32; g2 += 32; g3 += 32; g4 += 32; } while (0)

    // prologue: stage tiles 0,1
    STAGE(0);
    STAGE(10240);

#pragma unroll
    for (int t = 0; t < 16; ++t) {
        if (t < 15) { WAITV(5); }      // tile t's 5 loads done; tile t+1 in flight
        else        { WAITV(0); }
        __builtin_amdgcn_s_barrier();  // single barrier per K-step
        __builtin_amdgcn_sched_barrier(0);

        if (t < 14) STAGE(((t + 2) % 3) * 10240);   // overwrites buf read at t-1

        const unsigned short* cb = lds + (t % 3) * 10240;
#pragma unroll
        for (int ks = 0; ks < 2; ++ks) {
            bf16x8 af0 = *reinterpret_cast<const bf16x8*>(cb + aoff[0][ks]);
            bf16x8 bF  = *reinterpret_cast<const bf16x8*>(cb + 4096 + boff[ks]);
            bf16x8 af1 = *reinterpret_cast<const bf16x8*>(cb + aoff[1][ks]);
            bf16x8 bI  = *reinterpret_cast<const bf16x8*>(cb + 6144 + boff[ks]);
            bf16x8 bH  = *reinterpret_cast<const bf16x8*>(cb + 8192 + boff[ks]);
            __builtin_amdgcn_s_setprio(1);
            accF[0] = __builtin_amdgcn_mfma_f32_32x32x16_bf16(af0, bF, accF[0], 0, 0, 0);
            accF[1] = __builtin_amdgcn_mfma_f32_32x32x16_bf16(af1, bF, accF[1], 0, 0, 0);
            accI[0] = __builtin_amdgcn_mfma_f32_32x32x16_bf16(af0, bI, accI[0], 0, 0, 0);
            accI[1] = __builtin_amdgcn_mfma_f32_32x32x16_bf16(af1, bI, accI[1], 0, 0, 0);
            accH[0] = __builtin_amdgcn_mfma_f32_32x32x16_bf16(af0, bH, accH[0], 0, 0, 0);
            accH[1] = __builtin_amdgcn_mfma_f32_32x32x16_bf16(af1, bH, accH[1], 0, 0, 0);
            __builtin_amdgcn_s_setprio(0);
        }
        __builtin_amdgcn_sched_barrier(0);
    }
#undef STAGE

    // ---- epilogue: gates + packed au + full-chunk summary ----
    // C/D 32x32: col = lane&31 (n), row = (reg&3) + 8*(reg>>2) + 4*(lane>>5).
    const int n = nblk + wn * 32 + ln31;
    const float bfv = bf_[n], biv = bi_[n], bhv = bh_[n];
    const bool up = (lane & 32) != 0;
    float ca = 1.f, cu = 0.f;                  // chunk compose (64 rows, ascending)
#pragma unroll
    for (int mi = 0; mi < 2; ++mi) {
#pragma unroll
        for (int j = 0; j < 4; ++j) {          // 8-row block: rows mi*32 + 8j + 4*kh + r
            float sa = 1.f, su = 0.f;
#pragma unroll
            for (int r = 0; r < 4; ++r) {
                const int reg = 4 * j + r;
                const int m = mblk + wm * 64 + mi * 32 + 8 * j + 4 * kh + r;
                float zf = accF[mi][reg] + bfv;
                float zi = accI[mi][reg] + biv;
                float zh = accH[mi][reg] + bhv;
                float ef = __expf(-zf);
                float ei = __expf(-zi);
                float inv = __frcp_rn(2.0f + ef + ei);
                float av = (1.0f + ei) * inv;
                float uv = (1.0f + ef) * inv * zh;
                au_out[(size_t)m * 512 + n] =
                    ((unsigned int)f2bf(uv) << 16) | (unsigned int)f2bf(av);
                su = av * su + uv; sa *= av;   // compose rows ascending
            }
            // combine kh halves (rows +0..3 then +4..7) via xor-32 exchange
            float oa = __shfl_xor(sa, 32), ou = __shfl_xor(su, 32);
            float ta = sa * oa;
            float tu = up ? (sa * ou + su) : (oa * su + ou);
            // chunk := blk applied after chunk
            cu = ta * cu + tu; ca = ca * ta;
        }
    }
    if (lane < 32) {
        size_t ci = (size_t)(by * 2 + wm) * 512 + n;
        Asum[ci] = ca;
        Usum[ci] = cu;
    }
}

// ---------------- chunk-prefix (pass2) ----------------
__global__ void scan_pass2(const float4* __restrict__ Asum, const float4* __restrict__ Usum,
                           float4* __restrict__ Hinit) {
    int t = blockIdx.x * 256 + threadIdx.x;  // 0..1023
    int d4 = t & 127;
    int b = t >> 7;
    float4 h = {0.f, 0.f, 0.f, 0.f};
    for (int c = 0; c < NCHUNK; ++c) {
        size_t idx = (size_t)(b * NCHUNK + c) * 128 + d4;
        Hinit[idx] = h;
        float4 A = Asum[idx]; float4 U = Usum[idx];
        h.x = A.x * h.x + U.x; h.y = A.y * h.y + U.y;
        h.z = A.z * h.z + U.z; h.w = A.w * h.w + U.w;
    }
}

// ---------------- pass3 (layer 0): scan -> bf16 h ----------------
__global__ void scan_pass3(const uint4* __restrict__ au,
                           const float4* __restrict__ Hinit,
                           ushort4_t* __restrict__ hout) {
    int gid = blockIdx.x * 256 + threadIdx.x;   // 0..65535
    int d4 = gid & 127;
    int c  = (gid >> 7) & 63;
    int b  = gid >> 13;
    size_t base = (size_t)(b * TLEN + c * CLEN) * 128 + d4;
    size_t s4 = (size_t)(b * NCHUNK + c) * 128 + d4;
    float4 h0 = Hinit[s4];
    float h[4] = {h0.x, h0.y, h0.z, h0.w};
#pragma unroll 4
    for (int l = 0; l < CLEN; ++l) {
        size_t idx = base + (size_t)l * 128;
        uint4 v = au[idx];
        unsigned int vv[4] = {v.x, v.y, v.z, v.w};
        ushort4_t o;
#pragma unroll
        for (int j = 0; j < 4; ++j) {
            float av = __uint_as_float(vv[j] << 16);
            float uv = __uint_as_float(vv[j] & 0xFFFF0000u);
            h[j] = av * h[j] + uv;
            o[j] = f2bf(h[j]);
        }
        hout[idx] = o;
    }
}

// ---------------- pass3+residual+LN+proj fused (layer 1) ----------------
__global__ __launch_bounds__(128) void scan3_final(
    const uint4* __restrict__ au, const float4* __restrict__ Hinit,
    const float4* __restrict__ x4,
    const float* __restrict__ g, const float* __restrict__ bvec,
    const float* __restrict__ Wout, const float* __restrict__ bout,
    float* __restrict__ out)
{
    const int blk = blockIdx.x;            // 0..511 = b*64 + c
    const int b = blk >> 6, c = blk & 63;
    const int d4 = threadIdx.x;            // 0..127
    const int lane = threadIdx.x & 63;
    const int wv = threadIdx.x >> 6;

    float4 h0 = Hinit[(size_t)blk * 128 + d4];
    float h[4] = {h0.x, h0.y, h0.z, h0.w};
    float4 g4 = reinterpret_cast<const float4*>(g)[d4];
    float4 b4 = reinterpret_cast<const float4*>(bvec)[d4];
    float4 w4 = reinterpret_cast<const float4*>(Wout)[d4];
    const float ga[4] = {g4.x, g4.y, g4.z, g4.w};
    const float ba[4] = {b4.x, b4.y, b4.z, b4.w};
    const float wa[4] = {w4.x, w4.y, w4.z, w4.w};
    const float bo = bout[0];

    __shared__ float redS[2], redQ[2], redP[2];
    size_t base = ((size_t)b * TLEN + c * CLEN) * 128 + d4;

    for (int l = 0; l < CLEN; ++l) {
        size_t idx = base + (size_t)l * 128;
        uint4 v = au[idx];
        float4 xr = x4[idx];
        const unsigned int vv[4] = {v.x, v.y, v.z, v.w};
        const float xa[4] = {xr.x, xr.y, xr.z, xr.w};
        float r[4];
        float sfl = 0.f, q = 0.f;
#pragma unroll
        for (int j = 0; j < 4; ++j) {
            float av = __uint_as_float(vv[j] << 16);
            float uv = __uint_as_float(vv[j] & 0xFFFF0000u);
            h[j] = av * h[j] + uv;
            float hv = h[j];
            if (hv != hv) hv = xa[j];          // NaN fallback
            float rr = xa[j] + hv;
            r[j] = rr;
            sfl += rr; q += rr * rr;
        }
#pragma unroll
        for (int m = 32; m >= 1; m >>= 1) {
            sfl += __shfl_xor(sfl, m);
            q += __shfl_xor(q, m);
        }
        if (lane == 0) { redS[wv] = sfl; redQ[wv] = q; }
        __syncthreads();
        float st = redS[0] + redS[1];
        float qt = redQ[0] + redQ[1];
        float mu = st * (1.0f / 512.0f);
        float var = qt * (1.0f / 512.0f) - mu * mu;
        float rstd = rsqrtf(var + 1e-5f);
        float p = 0.f;
#pragma unroll
        for (int j = 0; j < 4; ++j)
            p += ((r[j] - mu) * rstd * ga[j] + ba[j]) * wa[j];
#pragma unroll
        for (int m = 32; m >= 1; m >>= 1) p += __shfl_xor(p, m);
        if (lane == 0) redP[wv] = p;
        __syncthreads();
        if (threadIdx.x == 0)
            out[(size_t)b * TLEN + c * CLEN + l] = redP[0] + redP[1] + bo;
    }
}

extern "C" void kernel_launch(void* const* d_in, const int* in_sizes, int n_in,
                              void* d_out, int out_size, void* d_ws, size_t ws_size,
                              hipStream_t stream) {
    const float* x    = (const float*)d_in[0];
    const float* Wf0  = (const float*)d_in[1];  const float* bf0 = (const float*)d_in[2];
    const float* Wi0  = (const float*)d_in[3];  const float* bi0 = (const float*)d_in[4];
    const float* Wh0  = (const float*)d_in[5];  const float* bh0 = (const float*)d_in[6];
    const float* Wf1  = (const float*)d_in[7];  const float* bf1 = (const float*)d_in[8];
    const float* Wi1  = (const float*)d_in[9];  const float* bi1 = (const float*)d_in[10];
    const float* Wh1  = (const float*)d_in[11]; const float* bh1 = (const float*)d_in[12];
    const float* ln_g = (const float*)d_in[13]; const float* ln_b = (const float*)d_in[14];
    const float* W_out = (const float*)d_in[15]; const float* b_out = (const float*)d_in[16];

    char* ws = (char*)d_ws;
    unsigned short* Xb = (unsigned short*)ws;  ws += (size_t)MROWS * DDIM * 2;   // 32 MB
    unsigned short* Wball = (unsigned short*)ws;
    unsigned short* Wb[6];
    for (int i = 0; i < 6; ++i) { Wb[i] = (unsigned short*)ws; ws += (size_t)DDIM * DDIM * 2; }
    unsigned int* aubuf = (unsigned int*)ws; ws += (size_t)MROWS * DDIM * 4;     // 64 MB packed a|u
    float* Asum = (float*)ws;  ws += (size_t)BSZ * NCHUNK * DDIM * 4;            // 1 MB
    float* Usum = (float*)ws;  ws += (size_t)BSZ * NCHUNK * DDIM * 4;
    float* Hinit = (float*)ws; ws += (size_t)BSZ * NCHUNK * DDIM * 4;
    unsigned short* h0b = (unsigned short*)ws; ws += (size_t)MROWS * DDIM * 2;   // 32 MB

    // merged casts
    cast_all<<<17920, 256, 0, stream>>>(
        (const float4*)x, (const float4*)Wf0, (const float4*)Wi0, (const float4*)Wh0,
        (const float4*)Wf1, (const float4*)Wi1, (const float4*)Wh1,
        (ushort4_t*)Xb, (ushort4_t*)Wball);

    // ---- layer 0 ----
    gates_gemm<<<2048, 256, 0, stream>>>(Xb, Wb[0], Wb[1], Wb[2], bf0, bi0, bh0,
                                         aubuf, Asum, Usum);
    scan_pass2<<<4, 256, 0, stream>>>((const float4*)Asum, (const float4*)Usum, (float4*)Hinit);
    scan_pass3<<<256, 256, 0, stream>>>((const uint4*)aubuf, (const float4*)Hinit, (ushort4_t*)h0b);

    // ---- layer 1 ----
    gates_gemm<<<2048, 256, 0, stream>>>(h0b, Wb[3], Wb[4], Wb[5], bf1, bi1, bh1,
                                         aubuf, Asum, Usum);
    scan_pass2<<<4, 256, 0, stream>>>((const float4*)Asum, (const float4*)Usum, (float4*)Hinit);
    scan3_final<<<512, 128, 0, stream>>>((const uint4*)aubuf, (const float4*)Hinit,
                                         (const float4*)x, ln_g, ln_b, W_out, b_out,
                                         (float*)d_out);
}

// Round 11
// 243.233 us; speedup vs baseline: 1.0139x; 1.0139x over previous
//
#include <hip/hip_runtime.h>
#include <hip/hip_bf16.h>
#include <stdint.h>

// B=8, T=4096, D=512, OUT=1. M = B*T = 32768.
// cast; fused gates GEMM (32x32x16 MFMA, BK=64 / 128B LDS rows, ring-2, fused
// chunk summaries); pass2; pass3 (L0) / pass3+LN+proj fused (L1).

#define MROWS 32768
#define DDIM  512
#define TLEN  4096
#define BSZ   8
#define NCHUNK 64
#define CLEN   64

typedef __attribute__((ext_vector_type(8))) __bf16 bf16x8;
typedef __attribute__((ext_vector_type(16))) float f32x16;
typedef __attribute__((ext_vector_type(4))) unsigned short ushort4_t;

static __device__ __forceinline__ unsigned short f2bf(float f) {
    unsigned int u = __float_as_uint(f);
    u = (u + 0x7FFFu + ((u >> 16) & 1u)) >> 16;   // RNE
    return (unsigned short)u;
}
static __device__ __forceinline__ float bf2f(unsigned short s) {
    return __uint_as_float(((unsigned int)s) << 16);
}
static __device__ __forceinline__ void gload_lds16(const void* gptr, void* ldsp) {
    __builtin_amdgcn_global_load_lds(
        (const __attribute__((address_space(1))) uint32_t*)gptr,
        (__attribute__((address_space(3))) uint32_t*)ldsp,
        16, 0, 0);
}

#define WAITV(n) asm volatile("s_waitcnt vmcnt(" #n ")" ::: "memory")

// ---------------- merged fp32 -> bf16 cast (x + 6 W) ----------------
__global__ __launch_bounds__(256) void cast_all(
    const float4* __restrict__ x,
    const float4* __restrict__ w0, const float4* __restrict__ w1,
    const float4* __restrict__ w2, const float4* __restrict__ w3,
    const float4* __restrict__ w4, const float4* __restrict__ w5,
    ushort4_t* __restrict__ xb, ushort4_t* __restrict__ wb)
{
    int i = blockIdx.x * 256 + threadIdx.x;    // 0 .. 4587519
    float4 v;
    ushort4_t* dst;
    if (i < 4194304) {
        v = x[i];
        dst = xb + i;
    } else {
        int j = i - 4194304;
        int wsel = j >> 16;
        int rem = j & 65535;
        const float4* src = (wsel == 0) ? w0 : (wsel == 1) ? w1 : (wsel == 2) ? w2
                          : (wsel == 3) ? w3 : (wsel == 4) ? w4 : w5;
        v = src[rem];
        dst = wb + j;
    }
    ushort4_t o;
    o.x = f2bf(v.x); o.y = f2bf(v.y); o.z = f2bf(v.z); o.w = f2bf(v.w);
    *dst = o;
}

// ---------------- fused gate GEMM + chunk-summary epilogue ----------------
// 256 thr / 4 waves (2m x 2n), wave tile 64x32 via 32x32x16 MFMA (2 m-frags x
// 3 gates, acc 6x f32x16 = 96 AGPR). BM=128, BN=64, BK=64; 8 K-tiles.
// LDS: ring-2 x (A[128][128B] 16KB + 3x B[64][128B] 12KB) = 2 x 40KB = 80KB.
// 128B rows: each row owns a full bank line; 16B-chunk cPhys = cLog ^ (row&7)
// (rounds 4/6/7 measured 0 conflicts with this layout; 64B rows are
// structurally 4-way conflicted regardless of XOR -- rounds 5/9/10).
// Per K-tile: {STAGE t+1 (10 gload_lds); vmcnt(10) counted; barrier;
//              4x [5 ds_read_b128; setprio(1); 6 MFMA; setprio(0)]; barrier}.
__global__ __launch_bounds__(256, 2) void gates_gemm(
    const unsigned short* __restrict__ X,
    const unsigned short* __restrict__ Wf,
    const unsigned short* __restrict__ Wi,
    const unsigned short* __restrict__ Wh,
    const float* __restrict__ bf_, const float* __restrict__ bi_,
    const float* __restrict__ bh_,
    unsigned int* __restrict__ au_out,
    float* __restrict__ Asum, float* __restrict__ Usum)
{
    __shared__ __align__(16) unsigned short lds[2 * 20480];   // 80 KB

    const int tid  = threadIdx.x;
    const int lane = tid & 63;
    const int wave = tid >> 6;                 // 0..3
    const int wm = wave >> 1;                  // 0..1 : 64-row strip (= one chunk)
    const int wn = wave & 1;                   // 0..1 : 32-col strip
    const int ln31 = lane & 31;
    const int kh = lane >> 5;                  // k-half within 16-k MFMA step

    // XCD-aware bijective swizzle: 2048 blocks; 8 bx of one by adjacent per XCD.
    const int w = blockIdx.x;
    const int xcd = w & 7;
    const int s = w >> 3;                      // 0..255
    const int by = xcd * 32 + (s >> 3);        // 0..255
    const int bx = s & 7;                      // 0..7
    const int mblk = by * 128;
    const int nblk = bx * 64;

    // staging: thread -> (srow = tid>>3 in 0..31, phys chunk c8 = tid&7);
    // logical chunk = c8 ^ (srow&7); slice = 32 rows x 128B = 4KB, dest linear.
    const int srow = tid >> 3;
    const int c8   = tid & 7;
    const int cg   = (c8 ^ (srow & 7)) << 3;   // bf16 units (16B chunks)
    const int tid8 = tid * 8;                  // linear LDS dest (ushorts)
    const unsigned short* gA0 = X + (size_t)(mblk + srow) * 512 + cg;
    const unsigned short* gA1 = X + (size_t)(mblk + 32 + srow) * 512 + cg;
    const unsigned short* gA2 = X + (size_t)(mblk + 64 + srow) * 512 + cg;
    const unsigned short* gA3 = X + (size_t)(mblk + 96 + srow) * 512 + cg;
    const unsigned short* gF0 = Wf + (size_t)(nblk + srow) * 512 + cg;
    const unsigned short* gF1 = Wf + (size_t)(nblk + 32 + srow) * 512 + cg;
    const unsigned short* gI0 = Wi + (size_t)(nblk + srow) * 512 + cg;
    const unsigned short* gI1 = Wi + (size_t)(nblk + 32 + srow) * 512 + cg;
    const unsigned short* gH0 = Wh + (size_t)(nblk + srow) * 512 + cg;
    const unsigned short* gH1 = Wh + (size_t)(nblk + 32 + srow) * 512 + cg;

    // frag read offsets (ushorts): row*64 + ((2ks+kh)^(row&7))*8; row&7 == ln31&7.
    const int fl = ln31 & 7;
    int co[4];
#pragma unroll
    for (int ks = 0; ks < 4; ++ks)
        co[ks] = ((2 * ks + kh) ^ fl) << 3;
    const int abase0 = (wm * 64 + ln31) * 64;
    const int abase1 = (wm * 64 + 32 + ln31) * 64;
    const int bbase  = 8192 + (wn * 32 + ln31) * 64;

    f32x16 accF[2], accI[2], accH[2];
#pragma unroll
    for (int mi = 0; mi < 2; ++mi) {
#pragma unroll
        for (int e = 0; e < 16; ++e) { accF[mi][e] = 0.f; accI[mi][e] = 0.f; accH[mi][e] = 0.f; }
    }

#define STAGE(bb) do { \
    gload_lds16(gA0, lds + (bb) + tid8);             \
    gload_lds16(gA1, lds + (bb) + 2048  + tid8);     \
    gload_lds16(gA2, lds + (bb) + 4096  + tid8);     \
    gload_lds16(gA3, lds + (bb) + 6144  + tid8);     \
    gload_lds16(gF0, lds + (bb) + 8192  + tid8);     \
    gload_lds16(gF1, lds + (bb) + 10240 + tid8);     \
    gload_lds16(gI0, lds + (bb) + 12288 + tid8);     \
    gload_lds16(gI1, lds + (bb) + 14336 + tid8);     \
    gload_lds16(gH0, lds + (bb) + 16384 + tid8);     \
    gload_lds16(gH1, lds + (bb) + 18432 + tid8);     \
    gA0 += 64; gA1 += 64; gA2 += 64; gA3 += 64; gF0 += 64; \
    gF1 += 64; gI0 += 64; gI1 += 64; gH0 += 64; gH1 += 64; } while (0)

    STAGE(0);   // tile 0 -> buf0

#pragma unroll
    for (int t = 0; t < 8; ++t) {
        if (t < 7) {
            STAGE(((t + 1) & 1) * 20480);   // dest protected by t-1's end barrier
            WAITV(10);                       // tile t's 10 loads done; t+1 in flight
        } else {
            WAITV(0);
        }
        __builtin_amdgcn_s_barrier();
        __builtin_amdgcn_sched_barrier(0);

        const unsigned short* cb = lds + (t & 1) * 20480;
#pragma unroll
        for (int ks = 0; ks < 4; ++ks) {
            bf16x8 af0 = *reinterpret_cast<const bf16x8*>(cb + abase0 + co[ks]);
            bf16x8 bF  = *reinterpret_cast<const bf16x8*>(cb + bbase + co[ks]);
            bf16x8 af1 = *reinterpret_cast<const bf16x8*>(cb + abase1 + co[ks]);
            bf16x8 bI  = *reinterpret_cast<const bf16x8*>(cb + bbase + 4096 + co[ks]);
            bf16x8 bH  = *reinterpret_cast<const bf16x8*>(cb + bbase + 8192 + co[ks]);
            __builtin_amdgcn_s_setprio(1);
            accF[0] = __builtin_amdgcn_mfma_f32_32x32x16_bf16(af0, bF, accF[0], 0, 0, 0);
            accF[1] = __builtin_amdgcn_mfma_f32_32x32x16_bf16(af1, bF, accF[1], 0, 0, 0);
            accI[0] = __builtin_amdgcn_mfma_f32_32x32x16_bf16(af0, bI, accI[0], 0, 0, 0);
            accI[1] = __builtin_amdgcn_mfma_f32_32x32x16_bf16(af1, bI, accI[1], 0, 0, 0);
            accH[0] = __builtin_amdgcn_mfma_f32_32x32x16_bf16(af0, bH, accH[0], 0, 0, 0);
            accH[1] = __builtin_amdgcn_mfma_f32_32x32x16_bf16(af1, bH, accH[1], 0, 0, 0);
            __builtin_amdgcn_s_setprio(0);
        }
        __builtin_amdgcn_sched_barrier(0);
        __builtin_amdgcn_s_barrier();   // protects cb from next iteration's STAGE
        __builtin_amdgcn_sched_barrier(0);
    }
#undef STAGE

    // ---- epilogue: gates + packed au + full-chunk summary ----
    // C/D 32x32: col = lane&31 (n), row = (reg&3) + 8*(reg>>2) + 4*(lane>>5).
    const int n = nblk + wn * 32 + ln31;
    const float bfv = bf_[n], biv = bi_[n], bhv = bh_[n];
    const bool up = (lane & 32) != 0;
    float ca = 1.f, cu = 0.f;                  // chunk compose (64 rows, ascending)
#pragma unroll
    for (int mi = 0; mi < 2; ++mi) {
#pragma unroll
        for (int j = 0; j < 4; ++j) {          // 8-row block: rows mi*32 + 8j + 4*kh + r
            float sa = 1.f, su = 0.f;
#pragma unroll
            for (int r = 0; r < 4; ++r) {
                const int reg = 4 * j + r;
                const int m = mblk + wm * 64 + mi * 32 + 8 * j + 4 * kh + r;
                float zf = accF[mi][reg] + bfv;
                float zi = accI[mi][reg] + biv;
                float zh = accH[mi][reg] + bhv;
                float ef = __expf(-zf);
                float ei = __expf(-zi);
                float inv = __frcp_rn(2.0f + ef + ei);
                float av = (1.0f + ei) * inv;
                float uv = (1.0f + ef) * inv * zh;
                au_out[(size_t)m * 512 + n] =
                    ((unsigned int)f2bf(uv) << 16) | (unsigned int)f2bf(av);
                su = av * su + uv; sa *= av;   // compose rows ascending
            }
            // combine kh halves (rows +0..3 then +4..7) via xor-32 exchange
            float oa = __shfl_xor(sa, 32), ou = __shfl_xor(su, 32);
            float ta = sa * oa;
            float tu = up ? (sa * ou + su) : (oa * su + ou);
            // chunk := blk applied after chunk
            cu = ta * cu + tu; ca = ca * ta;
        }
    }
    if (lane < 32) {
        size_t ci = (size_t)(by * 2 + wm) * 512 + n;
        Asum[ci] = ca;
        Usum[ci] = cu;
    }
}

// ---------------- chunk-prefix (pass2) ----------------
__global__ void scan_pass2(const float4* __restrict__ Asum, const float4* __restrict__ Usum,
                           float4* __restrict__ Hinit) {
    int t = blockIdx.x * 256 + threadIdx.x;  // 0..1023
    int d4 = t & 127;
    int b = t >> 7;
    float4 h = {0.f, 0.f, 0.f, 0.f};
    for (int c = 0; c < NCHUNK; ++c) {
        size_t idx = (size_t)(b * NCHUNK + c) * 128 + d4;
        Hinit[idx] = h;
        float4 A = Asum[idx]; float4 U = Usum[idx];
        h.x = A.x * h.x + U.x; h.y = A.y * h.y + U.y;
        h.z = A.z * h.z + U.z; h.w = A.w * h.w + U.w;
    }
}

// ---------------- pass3 (layer 0): scan -> bf16 h ----------------
__global__ void scan_pass3(const uint4* __restrict__ au,
                           const float4* __restrict__ Hinit,
                           ushort4_t* __restrict__ hout) {
    int gid = blockIdx.x * 256 + threadIdx.x;   // 0..65535
    int d4 = gid & 127;
    int c  = (gid >> 7) & 63;
    int b  = gid >> 13;
    size_t base = (size_t)(b * TLEN + c * CLEN) * 128 + d4;
    size_t s4 = (size_t)(b * NCHUNK + c) * 128 + d4;
    float4 h0 = Hinit[s4];
    float h[4] = {h0.x, h0.y, h0.z, h0.w};
#pragma unroll 4
    for (int l = 0; l < CLEN; ++l) {
        size_t idx = base + (size_t)l * 128;
        uint4 v = au[idx];
        unsigned int vv[4] = {v.x, v.y, v.z, v.w};
        ushort4_t o;
#pragma unroll
        for (int j = 0; j < 4; ++j) {
            float av = __uint_as_float(vv[j] << 16);
            float uv = __uint_as_float(vv[j] & 0xFFFF0000u);
            h[j] = av * h[j] + uv;
            o[j] = f2bf(h[j]);
        }
        hout[idx] = o;
    }
}

// ---------------- pass3+residual+LN+proj fused (layer 1) ----------------
__global__ __launch_bounds__(128) void scan3_final(
    const uint4* __restrict__ au, const float4* __restrict__ Hinit,
    const float4* __restrict__ x4,
    const float* __restrict__ g, const float* __restrict__ bvec,
    const float* __restrict__ Wout, const float* __restrict__ bout,
    float* __restrict__ out)
{
    const int blk = blockIdx.x;            // 0..511 = b*64 + c
    const int b = blk >> 6, c = blk & 63;
    const int d4 = threadIdx.x;            // 0..127
    const int lane = threadIdx.x & 63;
    const int wv = threadIdx.x >> 6;

    float4 h0 = Hinit[(size_t)blk * 128 + d4];
    float h[4] = {h0.x, h0.y, h0.z, h0.w};
    float4 g4 = reinterpret_cast<const float4*>(g)[d4];
    float4 b4 = reinterpret_cast<const float4*>(bvec)[d4];
    float4 w4 = reinterpret_cast<const float4*>(Wout)[d4];
    const float ga[4] = {g4.x, g4.y, g4.z, g4.w};
    const float ba[4] = {b4.x, b4.y, b4.z, b4.w};
    const float wa[4] = {w4.x, w4.y, w4.z, w4.w};
    const float bo = bout[0];

    __shared__ float redS[2], redQ[2], redP[2];
    size_t base = ((size_t)b * TLEN + c * CLEN) * 128 + d4;

    for (int l = 0; l < CLEN; ++l) {
        size_t idx = base + (size_t)l * 128;
        uint4 v = au[idx];
        float4 xr = x4[idx];
        const unsigned int vv[4] = {v.x, v.y, v.z, v.w};
        const float xa[4] = {xr.x, xr.y, xr.z, xr.w};
        float r[4];
        float sfl = 0.f, q = 0.f;
#pragma unroll
        for (int j = 0; j < 4; ++j) {
            float av = __uint_as_float(vv[j] << 16);
            float uv = __uint_as_float(vv[j] & 0xFFFF0000u);
            h[j] = av * h[j] + uv;
            float hv = h[j];
            if (hv != hv) hv = xa[j];          // NaN fallback
            float rr = xa[j] + hv;
            r[j] = rr;
            sfl += rr; q += rr * rr;
        }
#pragma unroll
        for (int m = 32; m >= 1; m >>= 1) {
            sfl += __shfl_xor(sfl, m);
            q += __shfl_xor(q, m);
        }
        if (lane == 0) { redS[wv] = sfl; redQ[wv] = q; }
        __syncthreads();
        float st = redS[0] + redS[1];
        float qt = redQ[0] + redQ[1];
        float mu = st * (1.0f / 512.0f);
        float var = qt * (1.0f / 512.0f) - mu * mu;
        float rstd = rsqrtf(var + 1e-5f);
        float p = 0.f;
#pragma unroll
        for (int j = 0; j < 4; ++j)
            p += ((r[j] - mu) * rstd * ga[j] + ba[j]) * wa[j];
#pragma unroll
        for (int m = 32; m >= 1; m >>= 1) p += __shfl_xor(p, m);
        if (lane == 0) redP[wv] = p;
        __syncthreads();
        if (threadIdx.x == 0)
            out[(size_t)b * TLEN + c * CLEN + l] = redP[0] + redP[1] + bo;
    }
}

extern "C" void kernel_launch(void* const* d_in, const int* in_sizes, int n_in,
                              void* d_out, int out_size, void* d_ws, size_t ws_size,
                              hipStream_t stream) {
    const float* x    = (const float*)d_in[0];
    const float* Wf0  = (const float*)d_in[1];  const float* bf0 = (const float*)d_in[2];
    const float* Wi0  = (const float*)d_in[3];  const float* bi0 = (const float*)d_in[4];
    const float* Wh0  = (const float*)d_in[5];  const float* bh0 = (const float*)d_in[6];
    const float* Wf1  = (const float*)d_in[7];  const float* bf1 = (const float*)d_in[8];
    const float* Wi1  = (const float*)d_in[9];  const float* bi1 = (const float*)d_in[10];
    const float* Wh1  = (const float*)d_in[11]; const float* bh1 = (const float*)d_in[12];
    const float* ln_g = (const float*)d_in[13]; const float* ln_b = (const float*)d_in[14];
    const float* W_out = (const float*)d_in[15]; const float* b_out = (const float*)d_in[16];

    char* ws = (char*)d_ws;
    unsigned short* Xb = (unsigned short*)ws;  ws += (size_t)MROWS * DDIM * 2;   // 32 MB
    unsigned short* Wball = (unsigned short*)ws;
    unsigned short* Wb[6];
    for (int i = 0; i < 6; ++i) { Wb[i] = (unsigned short*)ws; ws += (size_t)DDIM * DDIM * 2; }
    unsigned int* aubuf = (unsigned int*)ws; ws += (size_t)MROWS * DDIM * 4;     // 64 MB packed a|u
    float* Asum = (float*)ws;  ws += (size_t)BSZ * NCHUNK * DDIM * 4;            // 1 MB
    float* Usum = (float*)ws;  ws += (size_t)BSZ * NCHUNK * DDIM * 4;
    float* Hinit = (float*)ws; ws += (size_t)BSZ * NCHUNK * DDIM * 4;
    unsigned short* h0b = (unsigned short*)ws; ws += (size_t)MROWS * DDIM * 2;   // 32 MB

    // merged casts
    cast_all<<<17920, 256, 0, stream>>>(
        (const float4*)x, (const float4*)Wf0, (const float4*)Wi0, (const float4*)Wh0,
        (const float4*)Wf1, (const float4*)Wi1, (const float4*)Wh1,
        (ushort4_t*)Xb, (ushort4_t*)Wball);

    // ---- layer 0 ----
    gates_gemm<<<2048, 256, 0, stream>>>(Xb, Wb[0], Wb[1], Wb[2], bf0, bi0, bh0,
                                         aubuf, Asum, Usum);
    scan_pass2<<<4, 256, 0, stream>>>((const float4*)Asum, (const float4*)Usum, (float4*)Hinit);
    scan_pass3<<<256, 256, 0, stream>>>((const uint4*)aubuf, (const float4*)Hinit, (ushort4_t*)h0b);

    // ---- layer 1 ----
    gates_gemm<<<2048, 256, 0, stream>>>(h0b, Wb[3], Wb[4], Wb[5], bf1, bi1, bh1,
                                         aubuf, Asum, Usum);
    scan_pass2<<<4, 256, 0, stream>>>((const float4*)Asum, (const float4*)Usum, (float4*)Hinit);
    scan3_final<<<512, 128, 0, stream>>>((const uint4*)aubuf, (const float4*)Hinit,
                                         (const float4*)x, ln_g, ln_b, W_out, b_out,
                                         (float*)d_out);
}